// Round 7
// baseline (162.362 us; speedup 1.0000x reference)
//
#include <hip/hip_runtime.h>
#include <math.h>

#define NB 64
#define NPG 1024
#define NFEAT 8
#define NTOT (NB * NPG)
#define TT 128                  // collapse tile edge
#define NTILE 36                // upper-triangular 8x8 tile pairs
#define NBLK (NB * NTILE)       // 2304 blocks

static constexpr float MIN_DIST = 2.9f;

#if __has_builtin(__builtin_amdgcn_sqrtf)
#define FAST_SQRT(x) __builtin_amdgcn_sqrtf(x)   // raw v_sqrt_f32, ~1 ulp
#else
#define FAST_SQRT(x) sqrtf(x)
#endif

// ws float layout:
//   WS_STATS + b*16 + q : per-batch stats (q: 0..2 pmin, 3..5 pmax,
//                         6..8 omin, 9..11 omax, 12 recon, 13 zpsum)
//   WS_V   + b  : node_features v per batch
//   WS_CNT + b  : electrode count per batch
//   WS_ELE + b  : electrode sum per batch
//   WS_DONE     : float completion counter. Poison 0xAAAAAAAA = -3.03e-13;
//                 first atomicAdd(1.0f) rounds to 1.0 exactly, so the counter
//                 is exact despite no zero-init.
//   WS_COLL + x : weighted collapse partial per block x (x < NBLK)
#define WS_STATS 0
#define WS_V     1024
#define WS_CNT   1088
#define WS_ELE   1152
#define WS_DONE  1216
#define WS_COLL  1280

// (ic,jc) for tile index s in [0,36): all pairs with ic <= jc
__constant__ unsigned char ICT[NTILE] = {
    0,0,0,0,0,0,0,0, 1,1,1,1,1,1,1, 2,2,2,2,2,2,
    3,3,3,3,3, 4,4,4,4, 5,5,5, 6,6, 7};
__constant__ unsigned char JCT[NTILE] = {
    0,1,2,3,4,5,6,7, 1,2,3,4,5,6,7, 2,3,4,5,6,7,
    3,4,5,6,7, 4,5,6,7, 5,6,7, 6,7, 7};

__device__ __forceinline__ float waveSum(float v) {
#pragma unroll
  for (int o = 32; o > 0; o >>= 1) v += __shfl_down(v, o, 64);
  return v;
}
__device__ __forceinline__ float waveMin(float v) {
#pragma unroll
  for (int o = 32; o > 0; o >>= 1) v = fminf(v, __shfl_down(v, o, 64));
  return v;
}
__device__ __forceinline__ float waveMax(float v) {
#pragma unroll
  for (int o = 32; o > 0; o >>= 1) v = fmaxf(v, __shfl_down(v, o, 64));
  return v;
}

// One (px,py,pz) vs one staged j-point.
#define PAIR(QX, QY, QZ)                                  \
  {                                                       \
    float dx = px - (QX), dy = py - (QY), dz = pz - (QZ); \
    float d2 = fmaf(dx, dx, fmaf(dy, dy, dz * dz));       \
    float dd = FAST_SQRT(d2);                             \
    float t = fmaxf(MIN_DIST - dd, 0.f);                  \
    acc = fmaf(t, t, acc);                                \
  }

// 2304 blocks x 128 threads. Block (b,s): collapse tile (ic<=jc), off-diag
// x2 by symmetry (t(i,j)^2 == t(j,i)^2 bit-exactly; negate-then-square is
// bit-identical). s==0 blocks also do the batch's stats + electrode term.
// The LAST block to finish (device-scope atomic counter) runs the final
// reduction and writes d_out — no separate dispatch.
__global__ __launch_bounds__(128) void main_kernel(
    const float* __restrict__ pred, const float* __restrict__ tru,
    const float* __restrict__ orig, const float* __restrict__ feat,
    float* __restrict__ ws, float* __restrict__ out) {
  __shared__ __align__(16) float sxx[TT], syy[TT], szz[TT];
  __shared__ float scoll[2];
  __shared__ float sst[16][2];
  __shared__ int slast;
  const int x = blockIdx.x;
  const int b = x / NTILE;
  const int s = x - b * NTILE;
  const int ic = ICT[s], jc = JCT[s];
  const int tid = threadIdx.x;
  const int wid = tid >> 6, lane = tid & 63;
  const float* pb = pred + (size_t)b * NPG * 3;

  // ---- stage j-tile (SoA, so the inner loop reads 3 x b128 per 4 j) ----
  {
    const int j = jc * TT + tid;
    sxx[tid] = pb[j*3+0]; syy[tid] = pb[j*3+1]; szz[tid] = pb[j*3+2];
  }
  const int i = ic * TT + tid;
  const float px = pb[i*3+0], py = pb[i*3+1], pz = pb[i*3+2];
  __syncthreads();

  // ---- collapse tile ----
  float acc = 0.f;
#pragma unroll 2
  for (int k = 0; k < TT; k += 4) {
    float4 qx = *(const float4*)&sxx[k];  // wave-uniform addr: broadcast,
    float4 qy = *(const float4*)&syy[k];  // conflict-free
    float4 qz = *(const float4*)&szz[k];
    PAIR(qx.x, qy.x, qz.x)
    PAIR(qx.y, qy.y, qz.y)
    PAIR(qx.z, qy.z, qz.z)
    PAIR(qx.w, qy.w, qz.w)
  }
  if (ic == jc) acc -= MIN_DIST * MIN_DIST;  // self-pair: d2==0 exactly
  else          acc += acc;                  // symmetric double-count
  acc = waveSum(acc);
  if (lane == 0) scoll[wid] = acc;
  __syncthreads();
  if (tid == 0) ws[WS_COLL + x] = scoll[0] + scoll[1];

  // ---- per-batch stats + electrode (one block per batch) ----
  if (s == 0) {
    const float* tb = tru  + (size_t)b * NPG * 3;
    const float* ob = orig + (size_t)b * NPG * 3;
    float pmn0 =  INFINITY, pmn1 =  INFINITY, pmn2 =  INFINITY;
    float pmx0 = -INFINITY, pmx1 = -INFINITY, pmx2 = -INFINITY;
    float omn0 =  INFINITY, omn1 =  INFINITY, omn2 =  INFINITY;
    float omx0 = -INFINITY, omx1 = -INFINITY, omx2 = -INFINITY;
    float rec = 0.f, zps = 0.f;
    for (int k = 0; k < 8; k++) {
      const int ii = k * TT + tid;
      float p0 = pb[ii*3+0], p1 = pb[ii*3+1], p2 = pb[ii*3+2];
      float t0 = tb[ii*3+0], t1 = tb[ii*3+1], t2 = tb[ii*3+2];
      float o0 = ob[ii*3+0], o1 = ob[ii*3+1], o2 = ob[ii*3+2];
      pmn0 = fminf(pmn0, p0); pmx0 = fmaxf(pmx0, p0);
      pmn1 = fminf(pmn1, p1); pmx1 = fmaxf(pmx1, p1);
      pmn2 = fminf(pmn2, p2); pmx2 = fmaxf(pmx2, p2);
      omn0 = fminf(omn0, o0); omx0 = fmaxf(omx0, o0);
      omn1 = fminf(omn1, o1); omx1 = fmaxf(omx1, o1);
      omn2 = fminf(omn2, o2); omx2 = fmaxf(omx2, o2);
      float d0 = p0 - t0, d1 = p1 - t1, d2 = p2 - t2;
      rec += d0*d0 + d1*d1 + d2*d2;
      zps += p2;
    }
    float r[14];
    r[0]  = waveMin(pmn0); r[1]  = waveMin(pmn1); r[2]  = waveMin(pmn2);
    r[3]  = waveMax(pmx0); r[4]  = waveMax(pmx1); r[5]  = waveMax(pmx2);
    r[6]  = waveMin(omn0); r[7]  = waveMin(omn1); r[8]  = waveMin(omn2);
    r[9]  = waveMax(omx0); r[10] = waveMax(omx1); r[11] = waveMax(omx2);
    r[12] = waveSum(rec);
    r[13] = waveSum(zps);
    if (lane == 0) {
#pragma unroll
      for (int q = 0; q < 14; q++) sst[q][wid] = r[q];
    }
    __syncthreads();
    if (tid == 0) {
      float* w = ws + WS_STATS + ((size_t)b << 4);
      float c[14];
#pragma unroll
      for (int q = 0; q < 3; q++) {
        c[q]     = fminf(sst[q][0],     sst[q][1]);
        c[q + 3] = fmaxf(sst[q + 3][0], sst[q + 3][1]);
        c[q + 6] = fminf(sst[q + 6][0], sst[q + 6][1]);
        c[q + 9] = fmaxf(sst[q + 9][0], sst[q + 9][1]);
      }
      c[12] = sst[12][0] + sst[12][1];
      c[13] = sst[13][0] + sst[13][1];
#pragma unroll
      for (int q = 0; q < 14; q++) w[q] = c[q];
      float zr = c[11] - c[8];
      sst[14][0] = c[8]  + 0.15f * zr;   // lo
      sst[15][0] = c[11] - 0.15f * zr;   // hi
      ws[WS_V + b] = feat[(size_t)b * NPG * NFEAT + (NFEAT - 3)];
    }
    __syncthreads();
    const float lo = sst[14][0], hi = sst[15][0];
    float cnt = 0.f, el = 0.f;
    for (int k = 0; k < 8; k++) {
      const int ii = k * TT + tid;
      float oz = ob[ii*3+2];
      if (oz <= lo || oz >= hi) {
        float e0 = pb[ii*3+0] - ob[ii*3+0];
        float e1 = pb[ii*3+1] - ob[ii*3+1];
        float e2 = pb[ii*3+2] - oz;
        cnt += 1.f;
        el += e0*e0 + e1*e1 + e2*e2;
      }
    }
    cnt = waveSum(cnt);
    el  = waveSum(el);
    if (lane == 0) { sst[0][wid] = cnt; sst[1][wid] = el; }
    __syncthreads();
    if (tid == 0) {
      ws[WS_CNT + b] = sst[0][0] + sst[0][1];
      ws[WS_ELE + b] = sst[1][0] + sst[1][1];
    }
  }

  // ---- completion: last block does the final reduction ----
  __threadfence();                       // release our global stores
  if (tid == 0) {
    float old = atomicAdd(&ws[WS_DONE], 1.0f);   // device-scope
    slast = (old > (float)NBLK - 1.5f) ? 1 : 0;
  }
  __syncthreads();
  if (slast) {
    __threadfence();                     // acquire others' stores

    float c = 0.f;
    for (int k = tid; k < NBLK; k += 128) c += ws[WS_COLL + k];
    c = waveSum(c);
    if (lane == 0) scoll[wid] = c;
    __syncthreads();

    if (tid < 64) {
      const float* w = ws + WS_STATS + ((size_t)tid << 4);
      float pmn2 = w[2];
      float pdx = w[3] - w[0], pdy = w[4] - w[1], pdz = w[5] - w[2];
      float odx = w[9] - w[6], ody = w[10] - w[7], odz = w[11] - w[8];
      float rec = w[12], zs = w[13];

      float rx = (pdx - odx) / (odx + 1e-8f);
      float ry = (pdy - ody) / (ody + 1e-8f);
      float rz = (pdz - odz) / (odz + 1e-8f);
      float vol = fmaxf(rx - 0.02f, 0.f) + fmaxf(ry - 0.02f, 0.f) +
                  2.f * fmaxf(rz, 0.f);

      float v = ws[WS_V + tid];
      float zcom = zs * (1.f / NPG);
      float znorm = (zcom - pmn2) / (pdz + 1e-8f);
      float target = (v > 0.f) ? 0.6f : 0.4f;
      float dd = znorm - target;
      float contrib = (fabsf(v) >= 1e-6f) ? dd * dd : 0.f;

      float cnt = ws[WS_CNT + tid];
      float el  = ws[WS_ELE + tid];

      vol = waveSum(vol);
      contrib = waveSum(contrib);
      rec = waveSum(rec);
      cnt = waveSum(cnt);
      el  = waveSum(el);

      if (tid == 0) {
        float ctot = scoll[0] + scoll[1];
        float o_recon  = rec / (float)(NTOT * 3);
        float o_volume = vol / (float)NB;
        float o_elec   = el / (cnt * 3.f);
        float o_coll   = ctot / ((float)NB * NPG * (NPG - 1));
        float o_field  = contrib / (float)NB;
        float total = 1.0f * o_recon + 10.0f * o_volume + 50.0f * o_elec +
                      5.0f * o_coll + 2.0f * o_field;
        out[0] = total;
        out[1] = o_recon;
        out[2] = o_volume;
        out[3] = o_elec;
        out[4] = o_coll;
        out[5] = o_field;
      }
    }
  }
}

extern "C" void kernel_launch(void* const* d_in, const int* in_sizes, int n_in,
                              void* d_out, int out_size, void* d_ws, size_t ws_size,
                              hipStream_t stream) {
  const float* pred = (const float*)d_in[0];
  const float* tru  = (const float*)d_in[1];
  const float* orig = (const float*)d_in[2];
  const float* feat = (const float*)d_in[3];
  float* ws  = (float*)d_ws;
  float* out = (float*)d_out;

  main_kernel<<<NBLK, 128, 0, stream>>>(pred, tru, orig, feat, ws, out);
}

// Round 8
// 85.352 us; speedup vs baseline: 1.9023x; 1.9023x over previous
//
#include <hip/hip_runtime.h>
#include <math.h>

#define NB 64
#define NPG 1024
#define NFEAT 8
#define NTOT (NB * NPG)
#define TT 128                  // collapse tile edge
#define NTILE 36                // upper-triangular 8x8 tile pairs
#define NBLK (NB * NTILE)       // 2304 blocks

static constexpr float MIN_DIST = 2.9f;

#if __has_builtin(__builtin_amdgcn_sqrtf)
#define FAST_SQRT(x) __builtin_amdgcn_sqrtf(x)   // raw v_sqrt_f32, ~1 ulp
#else
#define FAST_SQRT(x) sqrtf(x)
#endif

// ws float layout (every slot written before read; no zero-init needed):
//   WS_STATS + b*16 + q : per-batch stats (q: 0..2 pmin, 3..5 pmax,
//                         6..8 omin, 9..11 omax, 12 recon, 13 zpsum)
//   WS_V   + b  : node_features v per batch
//   WS_CNT + b  : electrode count per batch
//   WS_ELE + b  : electrode sum per batch
//   WS_COLL + x : weighted collapse partial per block x (x < NBLK)
// NOTE (R7 lesson): no in-kernel cross-block completion — per-block
// __threadfence + same-address atomic cost ~94 us on gfx950 (non-coherent
// per-XCD L2s make device-scope release fences us-class). The second
// dispatch below is the cheap sync.
#define WS_STATS 0
#define WS_V     1024
#define WS_CNT   1088
#define WS_ELE   1152
#define WS_COLL  1280

// (ic,jc) for tile index s in [0,36): all pairs with ic <= jc
__constant__ unsigned char ICT[NTILE] = {
    0,0,0,0,0,0,0,0, 1,1,1,1,1,1,1, 2,2,2,2,2,2,
    3,3,3,3,3, 4,4,4,4, 5,5,5, 6,6, 7};
__constant__ unsigned char JCT[NTILE] = {
    0,1,2,3,4,5,6,7, 1,2,3,4,5,6,7, 2,3,4,5,6,7,
    3,4,5,6,7, 4,5,6,7, 5,6,7, 6,7, 7};

__device__ __forceinline__ float waveSum(float v) {
#pragma unroll
  for (int o = 32; o > 0; o >>= 1) v += __shfl_down(v, o, 64);
  return v;
}
__device__ __forceinline__ float waveMin(float v) {
#pragma unroll
  for (int o = 32; o > 0; o >>= 1) v = fminf(v, __shfl_down(v, o, 64));
  return v;
}
__device__ __forceinline__ float waveMax(float v) {
#pragma unroll
  for (int o = 32; o > 0; o >>= 1) v = fmaxf(v, __shfl_down(v, o, 64));
  return v;
}

// One (px,py,pz) vs one staged j-point.
#define PAIR(QX, QY, QZ)                                  \
  {                                                       \
    float dx = px - (QX), dy = py - (QY), dz = pz - (QZ); \
    float d2 = fmaf(dx, dx, fmaf(dy, dy, dz * dz));       \
    float dd = FAST_SQRT(d2);                             \
    float t = fmaxf(MIN_DIST - dd, 0.f);                  \
    acc = fmaf(t, t, acc);                                \
  }

// 2304 blocks x 128 threads. Block (b,s): collapse tile (ic<=jc), off-diag
// x2 by symmetry (t(i,j)^2 == t(j,i)^2 bit-exactly; negate-then-square is
// bit-identical). s==0 blocks also do the batch's stats + electrode term.
__global__ __launch_bounds__(128) void main_kernel(
    const float* __restrict__ pred, const float* __restrict__ tru,
    const float* __restrict__ orig, const float* __restrict__ feat,
    float* __restrict__ ws) {
  __shared__ __align__(16) float sxx[TT], syy[TT], szz[TT];
  __shared__ float scoll[2];
  __shared__ float sst[16][2];
  const int x = blockIdx.x;
  const int b = x / NTILE;
  const int s = x - b * NTILE;
  const int ic = ICT[s], jc = JCT[s];
  const int tid = threadIdx.x;
  const int wid = tid >> 6, lane = tid & 63;
  const float* pb = pred + (size_t)b * NPG * 3;

  // ---- stage j-tile (SoA: inner loop reads 3 x ds_read_b128 per 4 j) ----
  {
    const int j = jc * TT + tid;
    sxx[tid] = pb[j*3+0]; syy[tid] = pb[j*3+1]; szz[tid] = pb[j*3+2];
  }
  const int i = ic * TT + tid;
  const float px = pb[i*3+0], py = pb[i*3+1], pz = pb[i*3+2];
  __syncthreads();

  // ---- collapse tile ----
  float acc = 0.f;
#pragma unroll 2
  for (int k = 0; k < TT; k += 4) {
    float4 qx = *(const float4*)&sxx[k];  // wave-uniform addr: broadcast,
    float4 qy = *(const float4*)&syy[k];  // conflict-free
    float4 qz = *(const float4*)&szz[k];
    PAIR(qx.x, qy.x, qz.x)
    PAIR(qx.y, qy.y, qz.y)
    PAIR(qx.z, qy.z, qz.z)
    PAIR(qx.w, qy.w, qz.w)
  }
  if (ic == jc) acc -= MIN_DIST * MIN_DIST;  // self-pair: d2==0 exactly
  else          acc += acc;                  // symmetric double-count
  acc = waveSum(acc);
  if (lane == 0) scoll[wid] = acc;
  __syncthreads();
  if (tid == 0) ws[WS_COLL + x] = scoll[0] + scoll[1];

  // ---- per-batch stats + electrode (one block per batch) ----
  if (s == 0) {
    const float* tb = tru  + (size_t)b * NPG * 3;
    const float* ob = orig + (size_t)b * NPG * 3;
    float pmn0 =  INFINITY, pmn1 =  INFINITY, pmn2 =  INFINITY;
    float pmx0 = -INFINITY, pmx1 = -INFINITY, pmx2 = -INFINITY;
    float omn0 =  INFINITY, omn1 =  INFINITY, omn2 =  INFINITY;
    float omx0 = -INFINITY, omx1 = -INFINITY, omx2 = -INFINITY;
    float rec = 0.f, zps = 0.f;
    for (int k = 0; k < 8; k++) {
      const int ii = k * TT + tid;
      float p0 = pb[ii*3+0], p1 = pb[ii*3+1], p2 = pb[ii*3+2];
      float t0 = tb[ii*3+0], t1 = tb[ii*3+1], t2 = tb[ii*3+2];
      float o0 = ob[ii*3+0], o1 = ob[ii*3+1], o2 = ob[ii*3+2];
      pmn0 = fminf(pmn0, p0); pmx0 = fmaxf(pmx0, p0);
      pmn1 = fminf(pmn1, p1); pmx1 = fmaxf(pmx1, p1);
      pmn2 = fminf(pmn2, p2); pmx2 = fmaxf(pmx2, p2);
      omn0 = fminf(omn0, o0); omx0 = fmaxf(omx0, o0);
      omn1 = fminf(omn1, o1); omx1 = fmaxf(omx1, o1);
      omn2 = fminf(omn2, o2); omx2 = fmaxf(omx2, o2);
      float d0 = p0 - t0, d1 = p1 - t1, d2 = p2 - t2;
      rec += d0*d0 + d1*d1 + d2*d2;
      zps += p2;
    }
    float r[14];
    r[0]  = waveMin(pmn0); r[1]  = waveMin(pmn1); r[2]  = waveMin(pmn2);
    r[3]  = waveMax(pmx0); r[4]  = waveMax(pmx1); r[5]  = waveMax(pmx2);
    r[6]  = waveMin(omn0); r[7]  = waveMin(omn1); r[8]  = waveMin(omn2);
    r[9]  = waveMax(omx0); r[10] = waveMax(omx1); r[11] = waveMax(omx2);
    r[12] = waveSum(rec);
    r[13] = waveSum(zps);
    if (lane == 0) {
#pragma unroll
      for (int q = 0; q < 14; q++) sst[q][wid] = r[q];
    }
    __syncthreads();
    if (tid == 0) {
      float* w = ws + WS_STATS + ((size_t)b << 4);
      float c[14];
#pragma unroll
      for (int q = 0; q < 3; q++) {
        c[q]     = fminf(sst[q][0],     sst[q][1]);
        c[q + 3] = fmaxf(sst[q + 3][0], sst[q + 3][1]);
        c[q + 6] = fminf(sst[q + 6][0], sst[q + 6][1]);
        c[q + 9] = fmaxf(sst[q + 9][0], sst[q + 9][1]);
      }
      c[12] = sst[12][0] + sst[12][1];
      c[13] = sst[13][0] + sst[13][1];
#pragma unroll
      for (int q = 0; q < 14; q++) w[q] = c[q];
      float zr = c[11] - c[8];
      sst[14][0] = c[8]  + 0.15f * zr;   // lo
      sst[15][0] = c[11] - 0.15f * zr;   // hi
      ws[WS_V + b] = feat[(size_t)b * NPG * NFEAT + (NFEAT - 3)];
    }
    __syncthreads();
    const float lo = sst[14][0], hi = sst[15][0];
    float cnt = 0.f, el = 0.f;
    for (int k = 0; k < 8; k++) {
      const int ii = k * TT + tid;
      float oz = ob[ii*3+2];
      if (oz <= lo || oz >= hi) {
        float e0 = pb[ii*3+0] - ob[ii*3+0];
        float e1 = pb[ii*3+1] - ob[ii*3+1];
        float e2 = pb[ii*3+2] - oz;
        cnt += 1.f;
        el += e0*e0 + e1*e1 + e2*e2;
      }
    }
    cnt = waveSum(cnt);
    el  = waveSum(el);
    if (lane == 0) { sst[0][wid] = cnt; sst[1][wid] = el; }
    __syncthreads();
    if (tid == 0) {
      ws[WS_CNT + b] = sst[0][0] + sst[0][1];
      ws[WS_ELE + b] = sst[1][0] + sst[1][1];
    }
  }
}

__global__ __launch_bounds__(256) void final_kernel(
    const float* __restrict__ ws, float* __restrict__ out) {
  const int tid = threadIdx.x;
  __shared__ float shc[4];

  // reduce collapse partials (2304 values over 256 threads)
  float c = 0.f;
  for (int k = tid; k < NBLK; k += 256) c += ws[WS_COLL + k];
  c = waveSum(c);
  if ((tid & 63) == 0) shc[tid >> 6] = c;
  __syncthreads();

  // per-batch terms: one lane per batch on wave 0
  if (tid < 64) {
    const float* w = ws + WS_STATS + ((size_t)tid << 4);
    float pmn2 = w[2];
    float pdx = w[3] - w[0], pdy = w[4] - w[1], pdz = w[5] - w[2];
    float odx = w[9] - w[6], ody = w[10] - w[7], odz = w[11] - w[8];
    float rec = w[12], zs = w[13];

    float rx = (pdx - odx) / (odx + 1e-8f);
    float ry = (pdy - ody) / (ody + 1e-8f);
    float rz = (pdz - odz) / (odz + 1e-8f);
    float vol = fmaxf(rx - 0.02f, 0.f) + fmaxf(ry - 0.02f, 0.f) +
                2.f * fmaxf(rz, 0.f);

    float v = ws[WS_V + tid];
    float zcom = zs * (1.f / NPG);
    float znorm = (zcom - pmn2) / (pdz + 1e-8f);
    float target = (v > 0.f) ? 0.6f : 0.4f;
    float dd = znorm - target;
    float contrib = (fabsf(v) >= 1e-6f) ? dd * dd : 0.f;

    float cnt = ws[WS_CNT + tid];
    float el  = ws[WS_ELE + tid];

    vol = waveSum(vol);
    contrib = waveSum(contrib);
    rec = waveSum(rec);
    cnt = waveSum(cnt);
    el  = waveSum(el);

    if (tid == 0) {
      float ctot = shc[0] + shc[1] + shc[2] + shc[3];
      float o_recon  = rec / (float)(NTOT * 3);
      float o_volume = vol / (float)NB;
      float o_elec   = el / (cnt * 3.f);
      float o_coll   = ctot / ((float)NB * NPG * (NPG - 1));
      float o_field  = contrib / (float)NB;
      float total = 1.0f * o_recon + 10.0f * o_volume + 50.0f * o_elec +
                    5.0f * o_coll + 2.0f * o_field;
      out[0] = total;
      out[1] = o_recon;
      out[2] = o_volume;
      out[3] = o_elec;
      out[4] = o_coll;
      out[5] = o_field;
    }
  }
}

extern "C" void kernel_launch(void* const* d_in, const int* in_sizes, int n_in,
                              void* d_out, int out_size, void* d_ws, size_t ws_size,
                              hipStream_t stream) {
  const float* pred = (const float*)d_in[0];
  const float* tru  = (const float*)d_in[1];
  const float* orig = (const float*)d_in[2];
  const float* feat = (const float*)d_in[3];
  float* ws  = (float*)d_ws;
  float* out = (float*)d_out;

  main_kernel<<<NBLK, 128, 0, stream>>>(pred, tru, orig, feat, ws);
  final_kernel<<<1, 256, 0, stream>>>(ws, out);
}

// Round 9
// 82.697 us; speedup vs baseline: 1.9633x; 1.0321x over previous
//
#include <hip/hip_runtime.h>
#include <math.h>

#define NB 64
#define NPG 1024
#define NFEAT 8
#define NTOT (NB * NPG)
#define TT 128                  // collapse tile edge
#define NTILE 36                // upper-triangular 8x8 tile pairs
#define NBLK (NB * NTILE)       // 2304 blocks

static constexpr float MIN_DIST = 2.9f;

#if __has_builtin(__builtin_amdgcn_sqrtf)
#define FAST_SQRT(x) __builtin_amdgcn_sqrtf(x)   // raw v_sqrt_f32, ~1 ulp
#else
#define FAST_SQRT(x) sqrtf(x)
#endif

// ws float layout (every slot written before read; no zero-init needed):
//   WS_STATS + b*16 + q : per-batch stats (q: 0..2 pmin, 3..5 pmax,
//                         6..8 omin, 9..11 omax, 12 recon, 13 zpsum)
//   WS_V   + b  : node_features v per batch
//   WS_CNT + b  : electrode count per batch
//   WS_ELE + b  : electrode sum per batch
//   WS_COLL + x : weighted collapse partial per block x (x < NBLK)
// NOTE (R7 lesson): no in-kernel cross-block completion — per-block
// __threadfence + same-address atomic cost ~94 us on gfx950 (non-coherent
// per-XCD L2s make device-scope release fences us-class). The second
// dispatch below is the cheap sync.
// NOTE (R8 lesson): AoS float4 LDS tile beats SoA 3xb128 here — at 4.5
// waves/SIMD the LDS port overlaps VALU anyway; SoA's extra address
// streams net negative (83.4 vs 85.4 us measured).
#define WS_STATS 0
#define WS_V     1024
#define WS_CNT   1088
#define WS_ELE   1152
#define WS_COLL  1280

// (ic,jc) for tile index s in [0,36): all pairs with ic <= jc
__constant__ unsigned char ICT[NTILE] = {
    0,0,0,0,0,0,0,0, 1,1,1,1,1,1,1, 2,2,2,2,2,2,
    3,3,3,3,3, 4,4,4,4, 5,5,5, 6,6, 7};
__constant__ unsigned char JCT[NTILE] = {
    0,1,2,3,4,5,6,7, 1,2,3,4,5,6,7, 2,3,4,5,6,7,
    3,4,5,6,7, 4,5,6,7, 5,6,7, 6,7, 7};

__device__ __forceinline__ float waveSum(float v) {
#pragma unroll
  for (int o = 32; o > 0; o >>= 1) v += __shfl_down(v, o, 64);
  return v;
}
__device__ __forceinline__ float waveMin(float v) {
#pragma unroll
  for (int o = 32; o > 0; o >>= 1) v = fminf(v, __shfl_down(v, o, 64));
  return v;
}
__device__ __forceinline__ float waveMax(float v) {
#pragma unroll
  for (int o = 32; o > 0; o >>= 1) v = fmaxf(v, __shfl_down(v, o, 64));
  return v;
}

// 2304 blocks x 128 threads. Block (b,s): collapse tile (ic<=jc), off-diag
// x2 by symmetry (t(i,j)^2 == t(j,i)^2 bit-exactly; negate-then-square is
// bit-identical). s==0 blocks also do the batch's stats + electrode term.
__global__ __launch_bounds__(128) void main_kernel(
    const float* __restrict__ pred, const float* __restrict__ tru,
    const float* __restrict__ orig, const float* __restrict__ feat,
    float* __restrict__ ws) {
  __shared__ float4 pts[TT];
  __shared__ float scoll[2];
  __shared__ float sst[16][2];
  const int x = blockIdx.x;
  const int b = x / NTILE;
  const int s = x - b * NTILE;
  const int ic = ICT[s], jc = JCT[s];
  const int tid = threadIdx.x;
  const int wid = tid >> 6, lane = tid & 63;
  const float* pb = pred + (size_t)b * NPG * 3;

  // ---- stage j-tile ----
  {
    const int j = jc * TT + tid;
    pts[tid] = make_float4(pb[j*3+0], pb[j*3+1], pb[j*3+2], 0.f);
  }
  const int i = ic * TT + tid;
  const float px = pb[i*3+0], py = pb[i*3+1], pz = pb[i*3+2];
  __syncthreads();

  // ---- collapse tile ----
  float acc = 0.f;
#pragma unroll 8
  for (int k = 0; k < TT; k++) {
    float4 pj = pts[k];  // wave-uniform address: LDS broadcast, conflict-free
    float dx = px - pj.x, dy = py - pj.y, dz = pz - pj.z;
    float d2 = fmaf(dx, dx, fmaf(dy, dy, dz * dz));   // >= 0 always
    float d = FAST_SQRT(d2);
    float t = fmaxf(MIN_DIST - d, 0.f);
    acc = fmaf(t, t, acc);
  }
  if (ic == jc) acc -= MIN_DIST * MIN_DIST;  // self-pair: d2==0 exactly
  else          acc += acc;                  // symmetric double-count
  acc = waveSum(acc);
  if (lane == 0) scoll[wid] = acc;
  __syncthreads();
  if (tid == 0) ws[WS_COLL + x] = scoll[0] + scoll[1];

  // ---- per-batch stats + electrode (one block per batch) ----
  if (s == 0) {
    const float* tb = tru  + (size_t)b * NPG * 3;
    const float* ob = orig + (size_t)b * NPG * 3;
    float pmn0 =  INFINITY, pmn1 =  INFINITY, pmn2 =  INFINITY;
    float pmx0 = -INFINITY, pmx1 = -INFINITY, pmx2 = -INFINITY;
    float omn0 =  INFINITY, omn1 =  INFINITY, omn2 =  INFINITY;
    float omx0 = -INFINITY, omx1 = -INFINITY, omx2 = -INFINITY;
    float rec = 0.f, zps = 0.f;
    for (int k = 0; k < 8; k++) {
      const int ii = k * TT + tid;
      float p0 = pb[ii*3+0], p1 = pb[ii*3+1], p2 = pb[ii*3+2];
      float t0 = tb[ii*3+0], t1 = tb[ii*3+1], t2 = tb[ii*3+2];
      float o0 = ob[ii*3+0], o1 = ob[ii*3+1], o2 = ob[ii*3+2];
      pmn0 = fminf(pmn0, p0); pmx0 = fmaxf(pmx0, p0);
      pmn1 = fminf(pmn1, p1); pmx1 = fmaxf(pmx1, p1);
      pmn2 = fminf(pmn2, p2); pmx2 = fmaxf(pmx2, p2);
      omn0 = fminf(omn0, o0); omx0 = fmaxf(omx0, o0);
      omn1 = fminf(omn1, o1); omx1 = fmaxf(omx1, o1);
      omn2 = fminf(omn2, o2); omx2 = fmaxf(omx2, o2);
      float d0 = p0 - t0, d1 = p1 - t1, d2 = p2 - t2;
      rec += d0*d0 + d1*d1 + d2*d2;
      zps += p2;
    }
    float r[14];
    r[0]  = waveMin(pmn0); r[1]  = waveMin(pmn1); r[2]  = waveMin(pmn2);
    r[3]  = waveMax(pmx0); r[4]  = waveMax(pmx1); r[5]  = waveMax(pmx2);
    r[6]  = waveMin(omn0); r[7]  = waveMin(omn1); r[8]  = waveMin(omn2);
    r[9]  = waveMax(omx0); r[10] = waveMax(omx1); r[11] = waveMax(omx2);
    r[12] = waveSum(rec);
    r[13] = waveSum(zps);
    if (lane == 0) {
#pragma unroll
      for (int q = 0; q < 14; q++) sst[q][wid] = r[q];
    }
    __syncthreads();
    if (tid == 0) {
      float* w = ws + WS_STATS + ((size_t)b << 4);
      float c[14];
#pragma unroll
      for (int q = 0; q < 3; q++) {
        c[q]     = fminf(sst[q][0],     sst[q][1]);
        c[q + 3] = fmaxf(sst[q + 3][0], sst[q + 3][1]);
        c[q + 6] = fminf(sst[q + 6][0], sst[q + 6][1]);
        c[q + 9] = fmaxf(sst[q + 9][0], sst[q + 9][1]);
      }
      c[12] = sst[12][0] + sst[12][1];
      c[13] = sst[13][0] + sst[13][1];
#pragma unroll
      for (int q = 0; q < 14; q++) w[q] = c[q];
      float zr = c[11] - c[8];
      sst[14][0] = c[8]  + 0.15f * zr;   // lo
      sst[15][0] = c[11] - 0.15f * zr;   // hi
      ws[WS_V + b] = feat[(size_t)b * NPG * NFEAT + (NFEAT - 3)];
    }
    __syncthreads();
    const float lo = sst[14][0], hi = sst[15][0];
    float cnt = 0.f, el = 0.f;
    for (int k = 0; k < 8; k++) {
      const int ii = k * TT + tid;
      float oz = ob[ii*3+2];
      if (oz <= lo || oz >= hi) {
        float e0 = pb[ii*3+0] - ob[ii*3+0];
        float e1 = pb[ii*3+1] - ob[ii*3+1];
        float e2 = pb[ii*3+2] - oz;
        cnt += 1.f;
        el += e0*e0 + e1*e1 + e2*e2;
      }
    }
    cnt = waveSum(cnt);
    el  = waveSum(el);
    if (lane == 0) { sst[0][wid] = cnt; sst[1][wid] = el; }
    __syncthreads();
    if (tid == 0) {
      ws[WS_CNT + b] = sst[0][0] + sst[0][1];
      ws[WS_ELE + b] = sst[1][0] + sst[1][1];
    }
  }
}

__global__ __launch_bounds__(256) void final_kernel(
    const float* __restrict__ ws, float* __restrict__ out) {
  const int tid = threadIdx.x;
  __shared__ float shc[4];

  // reduce collapse partials (2304 values over 256 threads)
  float c = 0.f;
  for (int k = tid; k < NBLK; k += 256) c += ws[WS_COLL + k];
  c = waveSum(c);
  if ((tid & 63) == 0) shc[tid >> 6] = c;
  __syncthreads();

  // per-batch terms: one lane per batch on wave 0
  if (tid < 64) {
    const float* w = ws + WS_STATS + ((size_t)tid << 4);
    float pmn2 = w[2];
    float pdx = w[3] - w[0], pdy = w[4] - w[1], pdz = w[5] - w[2];
    float odx = w[9] - w[6], ody = w[10] - w[7], odz = w[11] - w[8];
    float rec = w[12], zs = w[13];

    float rx = (pdx - odx) / (odx + 1e-8f);
    float ry = (pdy - ody) / (ody + 1e-8f);
    float rz = (pdz - odz) / (odz + 1e-8f);
    float vol = fmaxf(rx - 0.02f, 0.f) + fmaxf(ry - 0.02f, 0.f) +
                2.f * fmaxf(rz, 0.f);

    float v = ws[WS_V + tid];
    float zcom = zs * (1.f / NPG);
    float znorm = (zcom - pmn2) / (pdz + 1e-8f);
    float target = (v > 0.f) ? 0.6f : 0.4f;
    float dd = znorm - target;
    float contrib = (fabsf(v) >= 1e-6f) ? dd * dd : 0.f;

    float cnt = ws[WS_CNT + tid];
    float el  = ws[WS_ELE + tid];

    vol = waveSum(vol);
    contrib = waveSum(contrib);
    rec = waveSum(rec);
    cnt = waveSum(cnt);
    el  = waveSum(el);

    if (tid == 0) {
      float ctot = shc[0] + shc[1] + shc[2] + shc[3];
      float o_recon  = rec / (float)(NTOT * 3);
      float o_volume = vol / (float)NB;
      float o_elec   = el / (cnt * 3.f);
      float o_coll   = ctot / ((float)NB * NPG * (NPG - 1));
      float o_field  = contrib / (float)NB;
      float total = 1.0f * o_recon + 10.0f * o_volume + 50.0f * o_elec +
                    5.0f * o_coll + 2.0f * o_field;
      out[0] = total;
      out[1] = o_recon;
      out[2] = o_volume;
      out[3] = o_elec;
      out[4] = o_coll;
      out[5] = o_field;
    }
  }
}

extern "C" void kernel_launch(void* const* d_in, const int* in_sizes, int n_in,
                              void* d_out, int out_size, void* d_ws, size_t ws_size,
                              hipStream_t stream) {
  const float* pred = (const float*)d_in[0];
  const float* tru  = (const float*)d_in[1];
  const float* orig = (const float*)d_in[2];
  const float* feat = (const float*)d_in[3];
  float* ws  = (float*)d_ws;
  float* out = (float*)d_out;

  main_kernel<<<NBLK, 128, 0, stream>>>(pred, tru, orig, feat, ws);
  final_kernel<<<1, 256, 0, stream>>>(ws, out);
}